// Round 6
// baseline (311.542 us; speedup 1.0000x reference)
//
#include <hip/hip_runtime.h>

typedef unsigned short u16;
typedef unsigned int u32;
typedef __attribute__((ext_vector_type(8))) short short8;
typedef __attribute__((ext_vector_type(4))) short short4v;
typedef __attribute__((ext_vector_type(4))) float f32x4;

__device__ __forceinline__ u16 f2bf(float f) {
    u32 u = __float_as_uint(f);
    u32 r = (u + 0x7fffu + ((u >> 16) & 1u)) >> 16;   // RNE
    return (u16)r;
}
__device__ __forceinline__ float bf2f(u16 h) {
    return __uint_as_float(((u32)h) << 16);
}

__device__ __forceinline__ void gload_lds16(const void* g, void* l) {
    __builtin_amdgcn_global_load_lds((const __attribute__((address_space(1))) void*)g,
                                     (__attribute__((address_space(3))) void*)l, 16, 0, 0);
}

#define BARRIER() do { __builtin_amdgcn_sched_barrier(0); __builtin_amdgcn_s_barrier(); __builtin_amdgcn_sched_barrier(0); } while (0)
#define VMCNT(N)  asm volatile("s_waitcnt vmcnt(" #N ")" ::: "memory")

// one staging round: 256 thr x 16B = 4 KiB = 32 rows of 128B (wave w covers 8 rows)
#define STG1(ptr, LDG, LOFF, RBASE, kelem) \
    gload_lds16((ptr) + (size_t)(RBASE) * (LDG) + (kelem), lds + (LOFF) + ((RBASE) + (wid << 3)) * 128)

// A tile 128 rows = 4 rounds
#define STG_A(LOFF, kelem) do { \
    STG1(pA, LDA, LOFF, 0,  kelem); STG1(pA, LDA, LOFF, 32, kelem); \
    STG1(pA, LDA, LOFF, 64, kelem); STG1(pA, LDA, LOFF, 96, kelem); } while (0)
// B tile in round order 0,2,1,3 (rows 0-31, 64-95, 32-63, 96-127) so ph1's
// needed rows retire first under the vmcnt(2) gate
#define STG_B(LOFF, kelem) do { \
    STG1(pB, LDB, LOFF, 0,  kelem); STG1(pB, LDB, LOFF, 64, kelem); \
    STG1(pB, LDB, LOFF, 32, kelem); STG1(pB, LDB, LOFF, 96, kelem); } while (0)

template<int BOFF>
__device__ __forceinline__ void ld_a4(short8 (&a)[4][2], const char* lds, int arow, int c0, int c1) {
    #pragma unroll
    for (int mf = 0; mf < 4; ++mf) {
        a[mf][0] = *(const short8*)(lds + BOFF + mf * 2048 + arow + c0);
        a[mf][1] = *(const short8*)(lds + BOFF + mf * 2048 + arow + c1);
    }
}
template<int BOFF, int P>
__device__ __forceinline__ void ld_b2(short8 (&b)[2][2], const char* lds, int brow, int c0, int c1) {
    #pragma unroll
    for (int nf = 0; nf < 2; ++nf) {
        b[nf][0] = *(const short8*)(lds + BOFF + P * 4096 + nf * 2048 + brow + c0);
        b[nf][1] = *(const short8*)(lds + BOFF + P * 4096 + nf * 2048 + brow + c1);
    }
}

template<int P>
__device__ __forceinline__ void mfq2(f32x4 (&acc)[4][4], short8 (&a)[4][2], short8 (&b)[2][2]) {
    __builtin_amdgcn_s_setprio(1);
    #pragma unroll
    for (int mf = 0; mf < 4; ++mf)
        #pragma unroll
        for (int nf = 0; nf < 2; ++nf) {
            acc[mf][P * 2 + nf] = __builtin_amdgcn_mfma_f32_16x16x32_bf16(a[mf][0], b[nf][0], acc[mf][P * 2 + nf], 0, 0, 0);
            acc[mf][P * 2 + nf] = __builtin_amdgcn_mfma_f32_16x16x32_bf16(a[mf][1], b[nf][1], acc[mf][P * 2 + nf], 0, 0, 0);
        }
    __builtin_amdgcn_s_setprio(0);
}

// ---------------------------------------------------------------------------
// 128x128 bf16 GEMM, BK=64, 4 waves, 64 KiB LDS -> 2 blocks/CU.
// A [M][K] rm, B [N][K] rm. Per-wave output 64x64 (acc[4][4]).
// 2 phases per K-tile:
//   ph1: gate vmcnt(2), barrier, ld A(8)+B-pair0(4), stage next-A(4), 16 MFMA
//   ph2: gate vmcnt(4), barrier, ld B-pair1(4), stage next-B(4), 16 MFMA
// Steady-state vmem queue depth 8; gates retire exactly the operands needed.
// LDS: A0@0 B0@16K A1@32K B1@48K, each [128][64] bf16 (128B rows),
// 16B-slot swizzle LDS[row][s] = G[row][s ^ (row&7)].
// EPI: 0 = bf16 out + bias, 1 = bf16 out scaled, 2 = f32 out scaled
// ---------------------------------------------------------------------------
template<int EPI, int LDA, int LDB, int LDC, int K>
__global__ __launch_bounds__(256, 2)
void gemm2p(const u16* __restrict__ A, long long sA,
            const u16* __restrict__ B, long long sB,
            void* __restrict__ Cv, long long sC,
            const float* __restrict__ bias, float scale,
            int GX, int GY)
{
    extern __shared__ char lds[];
    const int tid  = threadIdx.x;
    const int wid  = tid >> 6;
    const int lane = tid & 63;

    // bijective XCD swizzle (all grids are multiples of 8)
    const int nwg = gridDim.x;
    int bid = blockIdx.x;
    bid = (bid & 7) * (nwg >> 3) + (bid >> 3);
    const int bx  = bid % GX;
    const int rem = bid / GX;
    const int by  = rem % GY;
    const long long z = rem / GY;

    const int bm = by * 128, bn = bx * 128;
    const u16* Atile = A + z * sA + (size_t)bm * LDA;
    const u16* Btile = B + z * sB + (size_t)bn * LDB;

    const int wm = wid >> 1, wn = wid & 1;
    const int l15   = lane & 15;
    const int lxor  = (lane & 7) << 4;
    const int khi   = (lane >> 4) << 4;
    const int colk0 = khi ^ lxor;
    const int colk1 = (64 + khi) ^ lxor;
    const int arow  = (wm * 64 + l15) * 128;
    const int brow  = (wn * 64 + l15) * 128;

    const int swz = ((lane & 7) ^ ((lane >> 3) & 7)) << 3;   // inverse-swizzled src col
    const u16* pA = Atile + (size_t)((wid << 3) + (lane >> 3)) * LDA + swz;
    const u16* pB = Btile + (size_t)((wid << 3) + (lane >> 3)) * LDB + swz;

    f32x4 acc[4][4];
    #pragma unroll
    for (int m = 0; m < 4; ++m)
        #pragma unroll
        for (int n = 0; n < 4; ++n)
            acc[m][n] = (f32x4){0.f, 0.f, 0.f, 0.f};

    // prologue: stage T0 -> buf0 (A then B) ; queue = 8
    STG_A(0, 0);
    STG_B(16384, 0);

    short8 a[4][2], b[2][2];
    const int NI = K >> 7;     // two K-tiles (buf0, buf1) per iteration

    for (int it = 0; it < NI; ++it) {
        const bool more = (it + 1 < NI);
        const int ka = (it << 7) + 64;    // K-offset staged into buf1 (this pair's 2nd tile)
        const int kb = (it << 7) + 128;   // K-offset staged into buf0 (next pair's 1st tile)

        // ---- tile 2t (buf0) ----
        VMCNT(2); BARRIER();              // A0 + B0{r0,r2} landed
        ld_a4<0>(a, lds, arow, colk0, colk1);
        ld_b2<16384, 0>(b, lds, brow, colk0, colk1);
        STG_A(32768, ka);
        mfq2<0>(acc, a, b);

        VMCNT(4); BARRIER();              // B0{r1,r3} landed
        ld_b2<16384, 1>(b, lds, brow, colk0, colk1);
        STG_B(49152, ka);
        mfq2<1>(acc, a, b);

        // ---- tile 2t+1 (buf1) ----
        VMCNT(2); BARRIER();              // A1 + B1{r0,r2} landed
        ld_a4<32768>(a, lds, arow, colk0, colk1);
        ld_b2<49152, 0>(b, lds, brow, colk0, colk1);
        if (more) STG_A(0, kb);
        mfq2<0>(acc, a, b);

        if (more) { VMCNT(4); } else { VMCNT(0); }   // B1{r1,r3} landed
        BARRIER();
        ld_b2<49152, 1>(b, lds, brow, colk0, colk1);
        if (more) STG_B(16384, kb);
        mfq2<1>(acc, a, b);
    }

    // epilogue. C/D map (m89): col = lane&15, row = 4*(lane>>4)+reg
    const int r0 = (lane >> 4) * 4;
    const int cc = lane & 15;
    #pragma unroll
    for (int nf = 0; nf < 4; ++nf) {
        const int col = bn + wn * 64 + nf * 16 + cc;
        const float badd = (EPI == 0) ? bias[col] : 0.f;
        #pragma unroll
        for (int mf = 0; mf < 4; ++mf) {
            const int row = bm + wm * 64 + mf * 16 + r0;
            #pragma unroll
            for (int r = 0; r < 4; ++r) {
                const float v = acc[mf][nf][r] * scale + badd;
                if (EPI == 2) ((float*)Cv + z * sC)[(size_t)(row + r) * LDC + col] = v;
                else          ((u16*)Cv + z * sC)[(size_t)(row + r) * LDC + col] = f2bf(v);
            }
        }
    }
}

// ---------------------------------------------------------------------------
__global__ __launch_bounds__(256)
void cvt_f32_bf16(const float* __restrict__ in, u16* __restrict__ out, int n8)
{
    const int i = blockIdx.x * 256 + threadIdx.x;
    if (i >= n8) return;
    const float4* p = (const float4*)in;
    const float4 a = p[2 * i], b = p[2 * i + 1];
    short8 o;
    o[0] = (short)f2bf(a.x); o[1] = (short)f2bf(a.y);
    o[2] = (short)f2bf(a.z); o[3] = (short)f2bf(a.w);
    o[4] = (short)f2bf(b.x); o[5] = (short)f2bf(b.y);
    o[6] = (short)f2bf(b.z); o[7] = (short)f2bf(b.w);
    ((short8*)out)[i] = o;
}

// W [1024][3072] f32 -> Wt [3072][1024] bf16
__global__ __launch_bounds__(256)
void cvt_w_t(const float* __restrict__ W, u16* __restrict__ Wt)
{
    __shared__ u16 T[32][33];
    const int tid = threadIdx.x;
    const int tr = tid >> 3;
    const int tc = (tid & 7) * 4;
    const int c0 = blockIdx.x * 32;
    const int r0 = blockIdx.y * 32;
    const float4 v = *(const float4*)&W[(size_t)(r0 + tr) * 3072 + c0 + tc];
    T[tr][tc + 0] = f2bf(v.x); T[tr][tc + 1] = f2bf(v.y);
    T[tr][tc + 2] = f2bf(v.z); T[tr][tc + 3] = f2bf(v.w);
    __syncthreads();
    short4v o;
    o[0] = (short)T[tc + 0][tr]; o[1] = (short)T[tc + 1][tr];
    o[2] = (short)T[tc + 2][tr]; o[3] = (short)T[tc + 3][tr];
    *(short4v*)&Wt[(size_t)(c0 + tr) * 1024 + r0 + tc] = o;
}

// qkv bf16 [B*2048][3072], V at cols 2048.. -> Vt [B][1024][2048]
__global__ __launch_bounds__(256)
void trans_v(const u16* __restrict__ qkv, u16* __restrict__ Vt)
{
    __shared__ u16 T[32][33];
    const int tid = threadIdx.x;
    const int tr = tid >> 3;
    const int tc = (tid & 7) * 4;
    const int e0 = blockIdx.x * 32;
    const int s0 = blockIdx.y * 32;
    const int b  = blockIdx.z;
    const short4v v = *(const short4v*)&qkv[(size_t)(b * 2048 + s0 + tr) * 3072 + 2048 + e0 + tc];
    T[tr][tc + 0] = (u16)v[0]; T[tr][tc + 1] = (u16)v[1];
    T[tr][tc + 2] = (u16)v[2]; T[tr][tc + 3] = (u16)v[3];
    __syncthreads();
    short4v o;
    o[0] = (short)T[tc + 0][tr]; o[1] = (short)T[tc + 1][tr];
    o[2] = (short)T[tc + 2][tr]; o[3] = (short)T[tc + 3][tr];
    *(short4v*)&Vt[(size_t)b * 1024 * 2048 + (size_t)(e0 + tr) * 2048 + s0 + tc] = o;
}

// in-place row softmax over 2048 bf16
__global__ __launch_bounds__(256)
void softmax_bf16(u16* __restrict__ S)
{
    u16* row = S + (size_t)blockIdx.x * 2048;
    const int tid  = threadIdx.x;
    const int wid  = tid >> 6;
    const int lane = tid & 63;
    __shared__ float red[4];

    const short8 v8 = *(const short8*)&row[tid * 8];
    float v[8];
    float m = -3.4e38f;
    #pragma unroll
    for (int j = 0; j < 8; ++j) { v[j] = bf2f((u16)v8[j]); m = fmaxf(m, v[j]); }
    #pragma unroll
    for (int off = 32; off; off >>= 1) m = fmaxf(m, __shfl_xor(m, off));
    if (lane == 0) red[wid] = m;
    __syncthreads();
    m = fmaxf(fmaxf(red[0], red[1]), fmaxf(red[2], red[3]));
    float s = 0.f;
    #pragma unroll
    for (int j = 0; j < 8; ++j) { v[j] = __expf(v[j] - m); s += v[j]; }
    #pragma unroll
    for (int off = 32; off; off >>= 1) s += __shfl_xor(s, off);
    __syncthreads();
    if (lane == 0) red[wid] = s;
    __syncthreads();
    s = red[0] + red[1] + red[2] + red[3];
    const float inv = 1.f / s;
    short8 o;
    #pragma unroll
    for (int j = 0; j < 8; ++j) o[j] = (short)f2bf(v[j] * inv);
    *(short8*)&row[tid * 8] = o;
}

// ---------------------------------------------------------------------------
extern "C" void kernel_launch(void* const* d_in, const int* in_sizes, int n_in,
                              void* d_out, int out_size, void* d_ws, size_t ws_size,
                              hipStream_t stream) {
    const float* x    = (const float*)d_in[0];   // [8,2048,1024]
    const float* W    = (const float*)d_in[1];   // [1024,3072]
    const float* bias = (const float*)d_in[2];   // [3072]
    float* out = (float*)d_out;                  // [8,2048,1024] f32

    const int B = 8, S = 2048, E = 1024, N3 = 3072;
    const int M = B * S;                         // 16384

    char* ws = (char*)d_ws;
    u16* xb   = (u16*)ws;                          // 32 MiB  [M][E]
    u16* Wtb  = (u16*)(ws + 33554432);             //  6 MiB  [3072][1024]
    u16* qkvb = (u16*)(ws + 39845888);             // 96 MiB  [M][3072]
    u16* Vtb  = (u16*)(ws + 140509184);            // 32 MiB  [B][1024][2048]
    u16* Sb   = (u16*)(ws + 174063616);            // 64 MiB full / 8 MiB per-batch

    const size_t need_full = 174063616ull + (size_t)B * S * S * 2;
    const bool full = ws_size >= need_full;
    const float sc = 1.0f / 32.0f;
    const int LDSB = 65536;

    // instantiations: <EPI, LDA, LDB, LDC, K>
    auto kQKV = gemm2p<0, 1024, 1024, 3072, 1024>;
    auto kQKT = gemm2p<1, 3072, 3072, 2048, 1024>;
    auto kPV  = gemm2p<2, 2048, 2048, 1024, 2048>;
    (void)hipFuncSetAttribute(reinterpret_cast<const void*>(kQKV),
                              hipFuncAttributeMaxDynamicSharedMemorySize, LDSB);
    (void)hipFuncSetAttribute(reinterpret_cast<const void*>(kQKT),
                              hipFuncAttributeMaxDynamicSharedMemorySize, LDSB);
    (void)hipFuncSetAttribute(reinterpret_cast<const void*>(kPV),
                              hipFuncAttributeMaxDynamicSharedMemorySize, LDSB);

    cvt_f32_bf16<<<dim3((M * E) / 8 / 256), 256, 0, stream>>>(x, xb, (M * E) / 8);
    cvt_w_t<<<dim3(96, 32), 256, 0, stream>>>(W, Wtb);

    // qkv = x @ W + b : grid 24 x 128 = 3072 blocks
    kQKV<<<dim3(24 * 128), 256, LDSB, stream>>>(xb, 0, Wtb, 0, qkvb, 0, bias, 1.0f, 24, 128);

    trans_v<<<dim3(32, 64, 8), 256, 0, stream>>>(qkvb, Vtb);

    if (full) {
        kQKT<<<dim3(16 * 16 * 8), 256, LDSB, stream>>>(
            qkvb, (long long)S * N3, qkvb + E, (long long)S * N3,
            Sb, (long long)S * S, nullptr, sc, 16, 16);
        softmax_bf16<<<dim3(B * S), 256, 0, stream>>>(Sb);
        kPV<<<dim3(8 * 16 * 8), 256, LDSB, stream>>>(
            Sb, (long long)S * S, Vtb, (long long)E * S,
            out, (long long)S * E, nullptr, 1.0f, 8, 16);
    } else {
        for (int b = 0; b < B; ++b) {
            const u16* Qb = qkvb + (size_t)b * S * N3;
            kQKT<<<dim3(16 * 16), 256, LDSB, stream>>>(
                Qb, 0, Qb + E, 0, Sb, 0, nullptr, sc, 16, 16);
            softmax_bf16<<<dim3(S), 256, 0, stream>>>(Sb);
            kPV<<<dim3(8 * 16), 256, LDSB, stream>>>(
                Sb, 0, Vtb + (size_t)b * E * S, 0,
                out + (size_t)b * S * E, 0, nullptr, 1.0f, 8, 16);
        }
    }
}

// Round 7
// 279.597 us; speedup vs baseline: 1.1143x; 1.1143x over previous
//
#include <hip/hip_runtime.h>

typedef unsigned short u16;
typedef unsigned int u32;
typedef __attribute__((ext_vector_type(8))) short short8;
typedef __attribute__((ext_vector_type(4))) short short4v;
typedef __attribute__((ext_vector_type(4))) float f32x4;

__device__ __forceinline__ u16 f2bf(float f) {
    u32 u = __float_as_uint(f);
    u32 r = (u + 0x7fffu + ((u >> 16) & 1u)) >> 16;   // RNE
    return (u16)r;
}
__device__ __forceinline__ float bf2f(u16 h) {
    return __uint_as_float(((u32)h) << 16);
}

__device__ __forceinline__ void gload_lds16(const void* g, void* l) {
    __builtin_amdgcn_global_load_lds((const __attribute__((address_space(1))) void*)g,
                                     (__attribute__((address_space(3))) void*)l, 16, 0, 0);
}

#define BARRIER() do { __builtin_amdgcn_sched_barrier(0); __builtin_amdgcn_s_barrier(); __builtin_amdgcn_sched_barrier(0); } while (0)
#define VMCNT(N)  asm volatile("s_waitcnt vmcnt(" #N ")" ::: "memory")

// stage one 128-row half (2 global_load_lds per thread; dest linear, src inverse-swizzled)
#define STAGE(ptr, LDG, LOFF, RBASE, kelem) \
    do { gload_lds16((ptr) + (size_t)(RBASE) * (LDG) + (kelem),        lds + (LOFF) + ((RBASE) + (wid << 3)) * 128); \
         gload_lds16((ptr) + (size_t)((RBASE) + 64) * (LDG) + (kelem), lds + (LOFF) + ((RBASE) + 64 + (wid << 3)) * 128); } while (0)

template<int ROFF, int QH>
__device__ __forceinline__ void ld_a(short8 (&a)[4][2], const char* lds, int arow, int c0, int c1) {
    #pragma unroll
    for (int mf = 0; mf < 4; ++mf) {
        a[mf][0] = *(const short8*)(lds + ROFF + QH * 16384 + mf * 2048 + arow + c0);
        a[mf][1] = *(const short8*)(lds + ROFF + QH * 16384 + mf * 2048 + arow + c1);
    }
}
template<int ROFF, int QH>
__device__ __forceinline__ void ld_b(short8 (&b)[2][2], const char* lds, int brow, int c0, int c1) {
    #pragma unroll
    for (int nf = 0; nf < 2; ++nf) {
        b[nf][0] = *(const short8*)(lds + ROFF + QH * 16384 + nf * 2048 + brow + c0);
        b[nf][1] = *(const short8*)(lds + ROFF + QH * 16384 + nf * 2048 + brow + c1);
    }
}

template<int QM, int QN>
__device__ __forceinline__ void mfq(f32x4 (&acc)[2][4][2][2], short8 (&a)[4][2], short8 (&b)[2][2]) {
    __builtin_amdgcn_s_setprio(1);
    #pragma unroll
    for (int mf = 0; mf < 4; ++mf)
        #pragma unroll
        for (int nf = 0; nf < 2; ++nf) {
            acc[QM][mf][QN][nf] = __builtin_amdgcn_mfma_f32_16x16x32_bf16(a[mf][0], b[nf][0], acc[QM][mf][QN][nf], 0, 0, 0);
            acc[QM][mf][QN][nf] = __builtin_amdgcn_mfma_f32_16x16x32_bf16(a[mf][1], b[nf][1], acc[QM][mf][QN][nf], 0, 0, 0);
        }
    __builtin_amdgcn_s_setprio(0);
}

// ---------------------------------------------------------------------------
// 256x256 8-phase bf16 GEMM, 1 barrier/phase, UNIFORM staging (~1 half/phase).
// A [M][K] rm, B [N][K] rm. Snake Q00->Q01->Q11->Q10; B halves held in regs.
// Stage slots (region last-read -> stage margin >=1 phase + barrier):
//   ph1: buf1.A-h1 (cur T+1)  ph3: buf0.B-h0<-T+2  ph4: buf0.B-h1<-T+2
//   ph5: buf0.A-h0<-T+2       ph6: buf0.A-h1<-T+2  ph7: buf1.B-h0+h1<-T+3
//   ph8: buf1.A-h0<-T+3
// Gates (FIFO-exact, retire exactly one buffer's 8 loads, distance >=3 phases):
//   ph1-top: VMCNT(6)  [buf0 ready]     ph5-top: VMCNT(4)  [buf1 ready]
// LDS 128 KiB: buf0A@0 buf0B@32768 buf1A@65536 buf1B@98304, [256][64] each,
// 16B-slot swizzle: LDS[row][s] = G[row][s ^ (row&7)].
// EPI: 0 = bf16 out + bias, 1 = bf16 out scaled, 2 = f32 out scaled
// ---------------------------------------------------------------------------
template<int EPI, int LDA, int LDB, int LDC, int K>
__global__ __launch_bounds__(512, 2)
void gemm8p(const u16* __restrict__ A, long long sA,
            const u16* __restrict__ B, long long sB,
            void* __restrict__ Cv, long long sC,
            const float* __restrict__ bias, float scale,
            int GX, int GY)
{
    extern __shared__ char lds[];
    const int tid  = threadIdx.x;
    const int wid  = tid >> 6;
    const int lane = tid & 63;

    // bijective XCD swizzle (all grids are multiples of 8)
    const int nwg = gridDim.x;
    int bid = blockIdx.x;
    bid = (bid & 7) * (nwg >> 3) + (bid >> 3);
    const int bx  = bid % GX;
    const int rem = bid / GX;
    const int by  = rem % GY;
    const long long z = rem / GY;

    const int bm = by * 256, bn = bx * 256;
    const u16* Atile = A + z * sA + (size_t)bm * LDA;
    const u16* Btile = B + z * sB + (size_t)bn * LDB;

    const int wm = wid >> 2, wn = wid & 3;
    const int l15   = lane & 15;
    const int lxor  = (lane & 7) << 4;
    const int khi   = (lane >> 4) << 4;
    const int colk0 = khi ^ lxor;
    const int colk1 = (64 + khi) ^ lxor;
    const int arow  = (wm * 64 + l15) * 128;
    const int brow  = (wn * 32 + l15) * 128;

    const int swz = ((lane & 7) ^ (lane >> 3)) << 3;   // inverse-swizzled src col (elems)
    const u16* pA = Atile + (size_t)((wid << 3) + (lane >> 3)) * LDA + swz;
    const u16* pB = Btile + (size_t)((wid << 3) + (lane >> 3)) * LDB + swz;

    f32x4 acc[2][4][2][2];
    #pragma unroll
    for (int i = 0; i < 2; ++i)
        #pragma unroll
        for (int m = 0; m < 4; ++m)
            #pragma unroll
            for (int j = 0; j < 2; ++j)
                #pragma unroll
                for (int n = 0; n < 2; ++n)
                    acc[i][m][j][n] = (f32x4){0.f, 0.f, 0.f, 0.f};

    // prologue: buf0 <- T0 (8 loads), buf1 <- T1 halves {A-h0, B-h0, B-h1} (6)
    STAGE(pA, LDA, 0,     0,   0);  STAGE(pA, LDA, 0,     128, 0);
    STAGE(pB, LDB, 32768, 0,   0);  STAGE(pB, LDB, 32768, 128, 0);
    STAGE(pA, LDA, 65536, 0,   64);
    STAGE(pB, LDB, 98304, 0,   64); STAGE(pB, LDB, 98304, 128, 64);
    VMCNT(6);
    BARRIER();

    short8 a[4][2], b0[2][2], b1[2][2];
    const int NI = K >> 7;     // two 64-wide K-tiles per iteration

    for (int it = 0; it < NI; ++it) {
        const bool more = (it + 1 < NI);
        const int kc1 = it * 128 + 64;     // current pair's 2nd tile (buf1)
        const int kn  = it * 128 + 128;    // T+2 (-> buf0)
        const int kn2 = kn + 64;           // T+3 (-> buf1)

        // ph1: gate buf0 ; Q00 buf0 ; stage buf1.A-h1 (completes T+1)
        VMCNT(6);
        ld_a<0, 0>(a, lds, arow, colk0, colk1);
        ld_b<32768, 0>(b0, lds, brow, colk0, colk1);
        STAGE(pA, LDA, 65536, 128, kc1);
        BARRIER(); mfq<0, 0>(acc, a, b0);
        // ph2: Q01 buf0
        ld_b<32768, 1>(b1, lds, brow, colk0, colk1);
        BARRIER(); mfq<0, 1>(acc, a, b1);
        // ph3: Q11 buf0 ; stage buf0.B-h0 <- T+2
        ld_a<0, 1>(a, lds, arow, colk0, colk1);
        if (more) STAGE(pB, LDB, 32768, 0, kn);
        BARRIER(); mfq<1, 1>(acc, a, b1);
        // ph4: Q10 buf0 (held regs) ; stage buf0.B-h1 <- T+2
        if (more) STAGE(pB, LDB, 32768, 128, kn);
        BARRIER(); mfq<1, 0>(acc, a, b0);
        // ph5: gate buf1 ; Q00 buf1 ; stage buf0.A-h0 <- T+2
        if (more) { VMCNT(4); } else { VMCNT(0); }
        ld_a<65536, 0>(a, lds, arow, colk0, colk1);
        ld_b<98304, 0>(b0, lds, brow, colk0, colk1);
        if (more) STAGE(pA, LDA, 0, 0, kn);
        BARRIER(); mfq<0, 0>(acc, a, b0);
        // ph6: Q01 buf1 ; stage buf0.A-h1 <- T+2
        ld_b<98304, 1>(b1, lds, brow, colk0, colk1);
        if (more) STAGE(pA, LDA, 0, 128, kn);
        BARRIER(); mfq<0, 1>(acc, a, b1);
        // ph7: Q11 buf1 ; stage buf1.B-h0+h1 <- T+3
        ld_a<65536, 1>(a, lds, arow, colk0, colk1);
        if (more) { STAGE(pB, LDB, 98304, 0, kn2); STAGE(pB, LDB, 98304, 128, kn2); }
        BARRIER(); mfq<1, 1>(acc, a, b1);
        // ph8: Q10 buf1 ; stage buf1.A-h0 <- T+3
        if (more) STAGE(pA, LDA, 65536, 0, kn2);
        BARRIER(); mfq<1, 0>(acc, a, b0);
    }

    // epilogue. C/D map (m89): col = lane&15, row = 4*(lane>>4)+reg
    const int r0 = (lane >> 4) * 4;
    const int cc = lane & 15;
    #pragma unroll
    for (int qn = 0; qn < 2; ++qn)
        #pragma unroll
        for (int nf = 0; nf < 2; ++nf) {
            const int col = bn + qn * 128 + wn * 32 + nf * 16 + cc;
            const float badd = (EPI == 0) ? bias[col] : 0.f;
            #pragma unroll
            for (int qm = 0; qm < 2; ++qm)
                #pragma unroll
                for (int mf = 0; mf < 4; ++mf) {
                    const int row = bm + qm * 128 + wm * 64 + mf * 16 + r0;
                    #pragma unroll
                    for (int r = 0; r < 4; ++r) {
                        const float v = acc[qm][mf][qn][nf][r] * scale + badd;
                        if (EPI == 2) ((float*)Cv + z * sC)[(size_t)(row + r) * LDC + col] = v;
                        else          ((u16*)Cv + z * sC)[(size_t)(row + r) * LDC + col] = f2bf(v);
                    }
                }
        }
}

// ---------------------------------------------------------------------------
__global__ __launch_bounds__(256)
void cvt_f32_bf16(const float* __restrict__ in, u16* __restrict__ out, int n8)
{
    const int i = blockIdx.x * 256 + threadIdx.x;
    if (i >= n8) return;
    const float4* p = (const float4*)in;
    const float4 a = p[2 * i], b = p[2 * i + 1];
    short8 o;
    o[0] = (short)f2bf(a.x); o[1] = (short)f2bf(a.y);
    o[2] = (short)f2bf(a.z); o[3] = (short)f2bf(a.w);
    o[4] = (short)f2bf(b.x); o[5] = (short)f2bf(b.y);
    o[6] = (short)f2bf(b.z); o[7] = (short)f2bf(b.w);
    ((short8*)out)[i] = o;
}

// W [1024][3072] f32 -> Wt [3072][1024] bf16
__global__ __launch_bounds__(256)
void cvt_w_t(const float* __restrict__ W, u16* __restrict__ Wt)
{
    __shared__ u16 T[32][33];
    const int tid = threadIdx.x;
    const int tr = tid >> 3;
    const int tc = (tid & 7) * 4;
    const int c0 = blockIdx.x * 32;
    const int r0 = blockIdx.y * 32;
    const float4 v = *(const float4*)&W[(size_t)(r0 + tr) * 3072 + c0 + tc];
    T[tr][tc + 0] = f2bf(v.x); T[tr][tc + 1] = f2bf(v.y);
    T[tr][tc + 2] = f2bf(v.z); T[tr][tc + 3] = f2bf(v.w);
    __syncthreads();
    short4v o;
    o[0] = (short)T[tc + 0][tr]; o[1] = (short)T[tc + 1][tr];
    o[2] = (short)T[tc + 2][tr]; o[3] = (short)T[tc + 3][tr];
    *(short4v*)&Wt[(size_t)(c0 + tr) * 1024 + r0 + tc] = o;
}

// qkv bf16 [B*2048][3072], V at cols 2048.. -> Vt [B][1024][2048]
__global__ __launch_bounds__(256)
void trans_v(const u16* __restrict__ qkv, u16* __restrict__ Vt)
{
    __shared__ u16 T[32][33];
    const int tid = threadIdx.x;
    const int tr = tid >> 3;
    const int tc = (tid & 7) * 4;
    const int e0 = blockIdx.x * 32;
    const int s0 = blockIdx.y * 32;
    const int b  = blockIdx.z;
    const short4v v = *(const short4v*)&qkv[(size_t)(b * 2048 + s0 + tr) * 3072 + 2048 + e0 + tc];
    T[tr][tc + 0] = (u16)v[0]; T[tr][tc + 1] = (u16)v[1];
    T[tr][tc + 2] = (u16)v[2]; T[tr][tc + 3] = (u16)v[3];
    __syncthreads();
    short4v o;
    o[0] = (short)T[tc + 0][tr]; o[1] = (short)T[tc + 1][tr];
    o[2] = (short)T[tc + 2][tr]; o[3] = (short)T[tc + 3][tr];
    *(short4v*)&Vt[(size_t)b * 1024 * 2048 + (size_t)(e0 + tr) * 2048 + s0 + tc] = o;
}

// in-place row softmax over 2048 bf16
__global__ __launch_bounds__(256)
void softmax_bf16(u16* __restrict__ S)
{
    u16* row = S + (size_t)blockIdx.x * 2048;
    const int tid  = threadIdx.x;
    const int wid  = tid >> 6;
    const int lane = tid & 63;
    __shared__ float red[4];

    const short8 v8 = *(const short8*)&row[tid * 8];
    float v[8];
    float m = -3.4e38f;
    #pragma unroll
    for (int j = 0; j < 8; ++j) { v[j] = bf2f((u16)v8[j]); m = fmaxf(m, v[j]); }
    #pragma unroll
    for (int off = 32; off; off >>= 1) m = fmaxf(m, __shfl_xor(m, off));
    if (lane == 0) red[wid] = m;
    __syncthreads();
    m = fmaxf(fmaxf(red[0], red[1]), fmaxf(red[2], red[3]));
    float s = 0.f;
    #pragma unroll
    for (int j = 0; j < 8; ++j) { v[j] = __expf(v[j] - m); s += v[j]; }
    #pragma unroll
    for (int off = 32; off; off >>= 1) s += __shfl_xor(s, off);
    __syncthreads();
    if (lane == 0) red[wid] = s;
    __syncthreads();
    s = red[0] + red[1] + red[2] + red[3];
    const float inv = 1.f / s;
    short8 o;
    #pragma unroll
    for (int j = 0; j < 8; ++j) o[j] = (short)f2bf(v[j] * inv);
    *(short8*)&row[tid * 8] = o;
}

// ---------------------------------------------------------------------------
extern "C" void kernel_launch(void* const* d_in, const int* in_sizes, int n_in,
                              void* d_out, int out_size, void* d_ws, size_t ws_size,
                              hipStream_t stream) {
    const float* x    = (const float*)d_in[0];   // [8,2048,1024]
    const float* W    = (const float*)d_in[1];   // [1024,3072]
    const float* bias = (const float*)d_in[2];   // [3072]
    float* out = (float*)d_out;                  // [8,2048,1024] f32

    const int B = 8, S = 2048, E = 1024, N3 = 3072;
    const int M = B * S;                         // 16384

    char* ws = (char*)d_ws;
    u16* xb   = (u16*)ws;                          // 32 MiB  [M][E]
    u16* Wtb  = (u16*)(ws + 33554432);             //  6 MiB  [3072][1024]
    u16* qkvb = (u16*)(ws + 39845888);             // 96 MiB  [M][3072]
    u16* Vtb  = (u16*)(ws + 140509184);            // 32 MiB  [B][1024][2048]
    u16* Sb   = (u16*)(ws + 174063616);            // 64 MiB full / 8 MiB per-batch

    const size_t need_full = 174063616ull + (size_t)B * S * S * 2;
    const bool full = ws_size >= need_full;
    const float sc = 1.0f / 32.0f;
    const int LDSB = 131072;

    // instantiations: <EPI, LDA, LDB, LDC, K>
    auto kQKV = gemm8p<0, 1024, 1024, 3072, 1024>;
    auto kQKT = gemm8p<1, 3072, 3072, 2048, 1024>;
    auto kPV  = gemm8p<2, 2048, 2048, 1024, 2048>;
    (void)hipFuncSetAttribute(reinterpret_cast<const void*>(kQKV),
                              hipFuncAttributeMaxDynamicSharedMemorySize, LDSB);
    (void)hipFuncSetAttribute(reinterpret_cast<const void*>(kQKT),
                              hipFuncAttributeMaxDynamicSharedMemorySize, LDSB);
    (void)hipFuncSetAttribute(reinterpret_cast<const void*>(kPV),
                              hipFuncAttributeMaxDynamicSharedMemorySize, LDSB);

    cvt_f32_bf16<<<dim3((M * E) / 8 / 256), 256, 0, stream>>>(x, xb, (M * E) / 8);
    cvt_w_t<<<dim3(96, 32), 256, 0, stream>>>(W, Wtb);

    // qkv = x @ W + b : grid 12 x 64
    kQKV<<<dim3(12 * 64), 512, LDSB, stream>>>(xb, 0, Wtb, 0, qkvb, 0, bias, 1.0f, 12, 64);

    trans_v<<<dim3(32, 64, 8), 256, 0, stream>>>(qkvb, Vtb);

    if (full) {
        kQKT<<<dim3(8 * 8 * 8), 512, LDSB, stream>>>(
            qkvb, (long long)S * N3, qkvb + E, (long long)S * N3,
            Sb, (long long)S * S, nullptr, sc, 8, 8);
        softmax_bf16<<<dim3(B * S), 256, 0, stream>>>(Sb);
        kPV<<<dim3(4 * 8 * 8), 512, LDSB, stream>>>(
            Sb, (long long)S * S, Vtb, (long long)E * S,
            out, (long long)S * E, nullptr, 1.0f, 4, 8);
    } else {
        for (int b = 0; b < B; ++b) {
            const u16* Qb = qkvb + (size_t)b * S * N3;
            kQKT<<<dim3(8 * 8), 512, LDSB, stream>>>(
                Qb, 0, Qb + E, 0, Sb, 0, nullptr, sc, 8, 8);
            softmax_bf16<<<dim3(S), 256, 0, stream>>>(Sb);
            kPV<<<dim3(4 * 8), 512, LDSB, stream>>>(
                Sb, 0, Vtb + (size_t)b * E * S, 0,
                out + (size_t)b * S * E, 0, nullptr, 1.0f, 4, 8);
        }
    }
}